// Round 6
// baseline (546.136 us; speedup 1.0000x reference)
//
#include <hip/hip_runtime.h>

#define NT      8
#define TD      100
#define FEAT    172
#define DIN     272     // FEAT + TD
#define KPAD    288     // padded K, 9 * 32
#define NKS     9       // KPAD / 32
#define OUTD    128
#define BM      64      // edges per tile
#define TWO_PI  6.283185307179586

typedef __bf16 bf16x8 __attribute__((ext_vector_type(8)));
typedef float  f32x4  __attribute__((ext_vector_type(4)));
typedef short  s16x8  __attribute__((ext_vector_type(8)));

__device__ __forceinline__ unsigned short f2bf(float f) {
    unsigned u = __builtin_bit_cast(unsigned, f);
    u += 0x7FFFu + ((u >> 16) & 1u);          // RNE
    return (unsigned short)(u >> 16);
}

// ---------------- dtype detection (int32 vs int64 edge_types) ----------------
__global__ void k_detect(const int* __restrict__ words, int* __restrict__ flag) {
    __shared__ int s_or;
    if (threadIdx.x == 0) s_or = 0;
    __syncthreads();
    int v  = words[2 * threadIdx.x + 1];
    int v2 = words[2 * (threadIdx.x + 256) + 1];
    if (v | v2) atomicOr(&s_or, 1);
    __syncthreads();
    if (threadIdx.x == 0) *flag = (s_or == 0) ? 1 : 0;   // 1 => int64
}

__device__ __forceinline__ int get_type(const int* __restrict__ p, int e, int is64) {
    return p[is64 ? (2 * e) : e] & 7;
}

__global__ void k_init(int* diag) {
    if (threadIdx.x < 2) diag[threadIdx.x] = 0;
}

// ---------------- table prep ----------------
// freq_base[j]   = 10^(-j/11) / 2pi          (revolutions, type-0 base)
// freq_rad[t,j]  = 10^(-j/11) * (1+0.1t)     (radians, for e2e check)
// bias[t,n]      = b[t,n] + temb[t,n]
__global__ void k_prep_tables(const float* __restrict__ b, const float* __restrict__ temb,
                              float* __restrict__ freq_base, float* __restrict__ freq_rad,
                              float* __restrict__ bias) {
    int gid = blockIdx.x * blockDim.x + threadIdx.x;
    if (gid < TD)
        freq_base[gid] = (float)(pow(10.0, -(double)gid / 11.0) / TWO_PI);
    if (gid < NT * TD) {
        int t = gid / TD, j = gid - t * TD;
        freq_rad[gid] = (float)(pow(10.0, -(double)j / 11.0) * (1.0 + 0.1 * (double)t));
    }
    if (gid < NT * OUTD) bias[gid] = b[gid] + temb[gid];
}

// W[t][k][n] fp32 -> bf16 fragment order: bfrag[(((t*NKS+s)*8+nf)*64+lane)*8+i]
// lane: col = nf*16 + (lane&15), k = s*32 + (lane>>4)*8 + i   [HW-verified R3]
__global__ void k_prep_bfrag(const float* __restrict__ W, unsigned short* __restrict__ bfrag) {
    int gid = blockIdx.x * blockDim.x + threadIdx.x;
    if (gid >= NT * NKS * 8 * 64) return;
    int lane = gid & 63;
    int rest = gid >> 6;
    int nf = rest & 7; rest >>= 3;
    int s = rest % NKS, t = rest / NKS;
    int n  = nf * 16 + (lane & 15);
    int kb = s * 32 + (lane >> 4) * 8;
    unsigned short v[8];
    #pragma unroll
    for (int i = 0; i < 8; ++i) {
        int k = kb + i;
        float x = (k < DIN) ? W[((size_t)t * DIN + k) * OUTD + n] : 0.0f;
        v[i] = f2bf(x);
    }
    unsigned short* dst = bfrag + (size_t)gid * 8;
    #pragma unroll
    for (int i = 0; i < 8; ++i) dst[i] = v[i];
}

// ---------------- main kernel: NO bucketing, per-type MFMA passes ----------------
// Tile = 64 consecutive edges. Wave w owns output cols [w*32, w*32+32).
// For each type t present in tile: accumulate full K, store rows whose type==t.
__global__ __launch_bounds__(256) void k_main(
    const float* __restrict__ feats, const float* __restrict__ ts,
    const int* __restrict__ types, const int* __restrict__ flag,
    float* __restrict__ out, const float* __restrict__ freq_base,
    const float* __restrict__ bias_tab, const unsigned short* __restrict__ bfrag,
    int E)
{
    __shared__ __align__(16) unsigned short a_lds[4 * NKS * 64 * 8];  // 36864 B
    __shared__ int   trow_lds[BM];
    __shared__ float tsm_lds[BM];      // ts[e] * (1 + 0.1*t)
    __shared__ float freq_lds[TD];
    __shared__ int   umask;

    const int tid = threadIdx.x;
    const long base_e = (long)blockIdx.x * BM;

    if (tid == 0) umask = 0;
    if (tid < TD) freq_lds[tid] = freq_base[tid];
    __syncthreads();

    if (tid < BM) {
        long e = base_e + tid;
        int t = -1; float tsm = 0.0f;
        if (e < (long)E) {
            t = get_type(types, (int)e, *flag);
            tsm = ts[e] * (1.0f + 0.1f * (float)t);
            atomicOr(&umask, 1 << t);
        }
        trow_lds[tid] = t;
        tsm_lds[tid]  = tsm;
    }
    __syncthreads();

    // ---- stage A, fragment layout (HW-verified): row r = (r&15) within
    // rowblock (r>>4); k -> (s = k>>5, h = (k&31)>>3, i = k&7)
    for (int idx = tid; idx < BM * 43; idx += 256) {
        int r = idx / 43, c = idx - r * 43;
        long e = base_e + r;
        float4 f = make_float4(0.f, 0.f, 0.f, 0.f);
        if (e < (long)E) f = ((const float4*)feats)[e * 43 + c];
        int k0 = c * 4;
        int s = k0 >> 5, h = (k0 & 31) >> 3, i0 = k0 & 7;
        int base = (((r >> 4) * NKS + s) * 64 + h * 16 + (r & 15)) * 8 + i0;
        ushort4 v;
        v.x = f2bf(f.x); v.y = f2bf(f.y); v.z = f2bf(f.z); v.w = f2bf(f.w);
        *(ushort4*)&a_lds[base] = v;
    }
    for (int idx = tid; idx < BM * TD; idx += 256) {
        int r = idx / TD, j = idx - r * TD;
        float rev = tsm_lds[r] * freq_lds[j];
        float fr  = rev - floorf(rev);
        float cv  = cosf(6.283185307179586f * fr);
        if (trow_lds[r] < 0) cv = 0.0f;
        int k = FEAT + j;
        int s = k >> 5, h = (k & 31) >> 3, i = k & 7;
        a_lds[(((r >> 4) * NKS + s) * 64 + h * 16 + (r & 15)) * 8 + i] = f2bf(cv);
    }
    for (int idx = tid; idx < BM * (KPAD - DIN); idx += 256) {
        int r = idx >> 4, kk = idx & 15, k = DIN + kk;
        int s = k >> 5, h = (k & 31) >> 3, i = k & 7;
        a_lds[(((r >> 4) * NKS + s) * 64 + h * 16 + (r & 15)) * 8 + i] = 0;
    }
    __syncthreads();

    const int w = tid >> 6, lane = tid & 63;
    const int hq = lane >> 4, l15 = lane & 15;
    const int mask = umask;

    // per-lane row types: row = rb*16 + hq*4 + rg  (C/D map, m89-verified)
    int tr[4][4];
    #pragma unroll
    for (int rb = 0; rb < 4; ++rb)
        #pragma unroll
        for (int rg = 0; rg < 4; ++rg)
            tr[rb][rg] = trow_lds[rb * 16 + hq * 4 + rg];

    const int col0 = w * 32 + l15;        // nf = 2w
    const int col1 = w * 32 + 16 + l15;   // nf = 2w+1

    f32x4 acc[4][2];
    #pragma unroll 1
    for (int t = 0; t < NT; ++t) {
        if (!((mask >> t) & 1)) continue;
        #pragma unroll
        for (int rb = 0; rb < 4; ++rb) {
            acc[rb][0] = (f32x4){0.f, 0.f, 0.f, 0.f};
            acc[rb][1] = (f32x4){0.f, 0.f, 0.f, 0.f};
        }
        const s16x8* bp = (const s16x8*)bfrag + (size_t)t * NKS * 8 * 64;
        #pragma unroll 1
        for (int s = 0; s < NKS; ++s) {
            s16x8 b0 = bp[(s * 8 + 2 * w + 0) * 64 + lane];
            s16x8 b1 = bp[(s * 8 + 2 * w + 1) * 64 + lane];
            bf16x8 bb0 = __builtin_bit_cast(bf16x8, b0);
            bf16x8 bb1 = __builtin_bit_cast(bf16x8, b1);
            #pragma unroll
            for (int rb = 0; rb < 4; ++rb) {
                s16x8 araw = *(const s16x8*)&a_lds[((rb * NKS + s) * 64 + lane) * 8];
                bf16x8 a = __builtin_bit_cast(bf16x8, araw);
                acc[rb][0] = __builtin_amdgcn_mfma_f32_16x16x32_bf16(a, bb0, acc[rb][0], 0, 0, 0);
                acc[rb][1] = __builtin_amdgcn_mfma_f32_16x16x32_bf16(a, bb1, acc[rb][1], 0, 0, 0);
            }
        }
        const float bias0 = bias_tab[t * OUTD + col0];
        const float bias1 = bias_tab[t * OUTD + col1];
        #pragma unroll
        for (int rb = 0; rb < 4; ++rb)
            #pragma unroll
            for (int rg = 0; rg < 4; ++rg)
                if (tr[rb][rg] == t) {
                    long e = base_e + rb * 16 + hq * 4 + rg;   // valid: tr>=0 => e<E
                    out[(size_t)e * OUTD + col0] = acc[rb][0][rg] + bias0;
                    out[(size_t)e * OUTD + col1] = acc[rb][1][rg] + bias1;
                }
    }
}

// ---------------- sampled end-to-end verification (1/31 edges) ----------------
__global__ __launch_bounds__(128) void k_e2e(
    const float* __restrict__ feats, const float* __restrict__ ts,
    const int* __restrict__ types, const int* __restrict__ flag,
    const float* __restrict__ W, const float* __restrict__ b,
    const float* __restrict__ temb, const float* __restrict__ freq_rad,
    const float* __restrict__ out, int E, int* __restrict__ diag)
{
    __shared__ float srow[DIN];
    __shared__ int s_badcnt, s_big;
    const long e = (long)blockIdx.x * 31;
    if (e >= (long)E) return;
    const int n = threadIdx.x;
    if (n == 0) { s_badcnt = 0; s_big = 0; }
    const int tt = get_type(types, (int)e, *flag);
    const float tse = ts[e];
    for (int k = n; k < FEAT; k += 128) srow[k] = feats[e * FEAT + k];
    for (int j = n; j < TD; j += 128)   srow[FEAT + j] = cosf(tse * freq_rad[tt * TD + j]);
    __syncthreads();

    float acc = b[tt * OUTD + n] + temb[tt * OUTD + n];
    const float* wcol = W + (size_t)tt * DIN * OUTD + n;
    #pragma unroll 4
    for (int k = 0; k < DIN; ++k) acc += srow[k] * wcol[(size_t)k * OUTD];

    float d = fabsf(out[(size_t)e * OUTD + n] - acc);
    if (d > 0.05f) { atomicAdd(&s_badcnt, 1); if (d > 1.0f) s_big = 1; }
    __syncthreads();
    if (n == 0 && s_badcnt > 0) {
        atomicAdd(&diag[1], s_badcnt);
        atomicOr(&diag[0], s_big ? 96 : 32);
    }
}

__global__ void k_sentinel(const int* __restrict__ diag, float* __restrict__ out, int code) {
    if (threadIdx.x == 0 && blockIdx.x == 0) {
        int bits = code ? code : diag[0];
        int cnt  = code ? 0 : min(diag[1], 900000);
        if (bits != 0) out[0] = 1.0e6f * (float)(1 + bits) + (float)cnt;
    }
}

// ---------------- launch ----------------
extern "C" void kernel_launch(void* const* d_in, const int* in_sizes, int n_in,
                              void* d_out, int out_size, void* d_ws, size_t ws_size,
                              hipStream_t stream) {
    const float* feats = (const float*)d_in[0];
    const float* ts    = (const float*)d_in[1];
    const int*   types = (const int*)d_in[2];
    const float* W     = (const float*)d_in[3];
    const float* b     = (const float*)d_in[4];
    const float* temb  = (const float*)d_in[5];
    float* out = (float*)d_out;
    const int E = in_sizes[1];

    char* ws = (char*)d_ws;
    auto align256 = [](size_t x) { return (x + 255) & ~(size_t)255; };
    int* flag = (int*)(ws + 0);
    int* diag = (int*)(ws + 16);      // 2 ints
    size_t o = 256;
    float* freq_base = (float*)(ws + o); o = align256(o + TD * 4);
    float* freq_rad  = (float*)(ws + o); o = align256(o + NT * TD * 4);
    float* bias      = (float*)(ws + o); o = align256(o + NT * OUTD * 4);
    unsigned short* bfrag = (unsigned short*)(ws + o);
    o = align256(o + (size_t)NT * NKS * 8 * 64 * 8 * 2);

    if (ws_size < o) {
        k_sentinel<<<1, 64, 0, stream>>>(nullptr, out, 4);
        return;
    }

    k_init<<<1, 64, 0, stream>>>(diag);
    k_detect<<<1, 256, 0, stream>>>(types, flag);
    k_prep_tables<<<8, 256, 0, stream>>>(b, temb, freq_base, freq_rad, bias);
    k_prep_bfrag<<<(NT * NKS * 8 * 64 + 255) / 256, 256, 0, stream>>>(W, bfrag);

    int ntiles = (E + BM - 1) / BM;
    k_main<<<ntiles, 256, 0, stream>>>(feats, ts, types, flag, out,
                                       freq_base, bias, bfrag, E);

    k_e2e<<<(E + 30) / 31, 128, 0, stream>>>(feats, ts, types, flag, W, b, temb,
                                             freq_rad, out, E, diag);
    k_sentinel<<<1, 64, 0, stream>>>(diag, out, 0);
}

// Round 7
// 468.988 us; speedup vs baseline: 1.1645x; 1.1645x over previous
//
#include <hip/hip_runtime.h>

#define NT      8
#define TD      100
#define FEAT    172
#define DIN     272     // FEAT + TD
#define KPAD    288     // padded K, 9 * 32
#define NKS     9       // KPAD / 32
#define OUTD    128
#define BM      64      // rows per MFMA sub-tile
#define WIN     512     // edges per block (8 sub-tiles)
#define NST     (WIN / BM)
#define TWO_PI  6.283185307179586

typedef __bf16 bf16x8 __attribute__((ext_vector_type(8)));
typedef float  f32x4  __attribute__((ext_vector_type(4)));
typedef short  s16x8  __attribute__((ext_vector_type(8)));

__device__ __forceinline__ unsigned short f2bf(float f) {
    unsigned u = __builtin_bit_cast(unsigned, f);
    u += 0x7FFFu + ((u >> 16) & 1u);          // RNE
    return (unsigned short)(u >> 16);
}

// ---------------- dtype detection (int32 vs int64 edge_types) ----------------
__global__ void k_detect(const int* __restrict__ words, int* __restrict__ flag) {
    __shared__ int s_or;
    if (threadIdx.x == 0) s_or = 0;
    __syncthreads();
    int v  = words[2 * threadIdx.x + 1];
    int v2 = words[2 * (threadIdx.x + 256) + 1];
    if (v | v2) atomicOr(&s_or, 1);
    __syncthreads();
    if (threadIdx.x == 0) *flag = (s_or == 0) ? 1 : 0;   // 1 => int64
}

__device__ __forceinline__ int get_type(const int* __restrict__ p, int e, int is64) {
    return p[is64 ? (2 * e) : e] & 7;
}

__global__ void k_init(int* diag) {
    if (threadIdx.x < 2) diag[threadIdx.x] = 0;
}

// ---------------- table prep ----------------
__global__ void k_prep_tables(const float* __restrict__ b, const float* __restrict__ temb,
                              float* __restrict__ freq_base, float* __restrict__ freq_rad,
                              float* __restrict__ bias) {
    int gid = blockIdx.x * blockDim.x + threadIdx.x;
    if (gid < TD)
        freq_base[gid] = (float)(pow(10.0, -(double)gid / 11.0) / TWO_PI);
    if (gid < NT * TD) {
        int t = gid / TD, j = gid - t * TD;
        freq_rad[gid] = (float)(pow(10.0, -(double)j / 11.0) * (1.0 + 0.1 * (double)t));
    }
    if (gid < NT * OUTD) bias[gid] = b[gid] + temb[gid];
}

// W[t][k][n] fp32 -> bf16 fragment order: bfrag[(((t*NKS+s)*8+nf)*64+lane)*8+i]
// lane: col = nf*16 + (lane&15), k = s*32 + (lane>>4)*8 + i   [HW-verified R3/R6]
__global__ void k_prep_bfrag(const float* __restrict__ W, unsigned short* __restrict__ bfrag) {
    int gid = blockIdx.x * blockDim.x + threadIdx.x;
    if (gid >= NT * NKS * 8 * 64) return;
    int lane = gid & 63;
    int rest = gid >> 6;
    int nf = rest & 7; rest >>= 3;
    int s = rest % NKS, t = rest / NKS;
    int n  = nf * 16 + (lane & 15);
    int kb = s * 32 + (lane >> 4) * 8;
    unsigned short v[8];
    #pragma unroll
    for (int i = 0; i < 8; ++i) {
        int k = kb + i;
        float x = (k < DIN) ? W[((size_t)t * DIN + k) * OUTD + n] : 0.0f;
        v[i] = f2bf(x);
    }
    unsigned short* dst = bfrag + (size_t)gid * 8;
    #pragma unroll
    for (int i = 0; i < 8; ++i) dst[i] = v[i];
}

// ---------------- main kernel: block-local type sort + per-segment MFMA ----------------
__global__ __launch_bounds__(256) void k_main(
    const float* __restrict__ feats, const float* __restrict__ ts,
    const int* __restrict__ types, const int* __restrict__ flag,
    float* __restrict__ out, const float* __restrict__ freq_base,
    const float* __restrict__ bias_tab, const unsigned short* __restrict__ bfrag,
    int E)
{
    __shared__ __align__(16) unsigned short a_lds[4 * NKS * 64 * 8];  // 36864 B
    __shared__ unsigned short pt[WIN];   // local_idx(9b) | type<<12 ; 0xFFFF = invalid
    __shared__ float tsm[WIN];           // ts[e] * (1 + 0.1*t), by sorted slot
    __shared__ float freq_lds[TD];
    __shared__ int cnt[NT];
    __shared__ int seg[NT + 1];
    __shared__ int um[NST];              // per-sub-tile type union mask

    const int tid = threadIdx.x;
    const long base_e = (long)blockIdx.x * WIN;
    const int is64 = *flag;

    if (tid < NT)  cnt[tid] = 0;
    if (tid < NST) um[tid] = 0;
    if (tid < TD)  freq_lds[tid] = freq_base[tid];
    pt[tid] = 0xFFFF; pt[tid + 256] = 0xFFFF;
    __syncthreads();

    // histogram (2 edges/thread) + coalesced ts/type reads
    int t0 = -1, t1 = -1; float f0 = 0.f, f1 = 0.f;
    {
        long e0 = base_e + tid, e1 = base_e + tid + 256;
        if (e0 < (long)E) { t0 = get_type(types, (int)e0, is64); f0 = ts[e0] * (1.0f + 0.1f * t0); atomicAdd(&cnt[t0], 1); }
        if (e1 < (long)E) { t1 = get_type(types, (int)e1, is64); f1 = ts[e1] * (1.0f + 0.1f * t1); atomicAdd(&cnt[t1], 1); }
    }
    __syncthreads();
    if (tid == 0) {
        int a = 0;
        #pragma unroll
        for (int t = 0; t < NT; ++t) { seg[t] = a; a += cnt[t]; cnt[t] = 0; }
        seg[NT] = a;
    }
    __syncthreads();
    if (t0 >= 0) {
        int r = seg[t0] + atomicAdd(&cnt[t0], 1);
        pt[r] = (unsigned short)(tid | (t0 << 12));
        tsm[r] = f0;
        atomicOr(&um[r >> 6], 1 << t0);
    }
    if (t1 >= 0) {
        int r = seg[t1] + atomicAdd(&cnt[t1], 1);
        pt[r] = (unsigned short)((tid + 256) | (t1 << 12));
        tsm[r] = f1;
        atomicOr(&um[r >> 6], 1 << t1);
    }
    __syncthreads();

    const int w = tid >> 6, lane = tid & 63;
    const int hq = lane >> 4, l15 = lane & 15;
    const int col0 = w * 32 + l15;        // nf = 2w
    const int col1 = w * 32 + 16 + l15;   // nf = 2w+1

    #pragma unroll 1
    for (int st = 0; st < NST; ++st) {
        const int rbase = st * BM;

        // ---- stage A: edge_feats (fragment layout, HW-verified)
        for (int idx = tid; idx < BM * 43; idx += 256) {
            int r = idx / 43, c = idx - r * 43;
            unsigned p = pt[rbase + r];
            float4 f = make_float4(0.f, 0.f, 0.f, 0.f);
            if (p != 0xFFFFu) f = ((const float4*)feats)[(base_e + (p & 0x1FF)) * 43 + c];
            int k0 = c * 4;
            int s = k0 >> 5, h = (k0 & 31) >> 3, i0 = k0 & 7;
            int base = (((r >> 4) * NKS + s) * 64 + h * 16 + (r & 15)) * 8 + i0;
            ushort4 v;
            v.x = f2bf(f.x); v.y = f2bf(f.y); v.z = f2bf(f.z); v.w = f2bf(f.w);
            *(ushort4*)&a_lds[base] = v;
        }
        // ---- stage A: time features via v_cos (revolutions)
        for (int idx = tid; idx < BM * TD; idx += 256) {
            int r = idx / TD, j = idx - r * TD;
            float rev = tsm[rbase + r] * freq_lds[j];
            float fr  = rev - floorf(rev);
            float cv  = __builtin_amdgcn_cosf(fr);     // cos(2*pi*fr)
            if (pt[rbase + r] == 0xFFFFu) cv = 0.0f;
            int k = FEAT + j;
            int s = k >> 5, h = (k & 31) >> 3, i = k & 7;
            a_lds[(((r >> 4) * NKS + s) * 64 + h * 16 + (r & 15)) * 8 + i] = f2bf(cv);
        }
        // ---- zero pad (cols 272..287)
        for (int idx = tid; idx < BM * (KPAD - DIN); idx += 256) {
            int r = idx >> 4, kk = idx & 15, k = DIN + kk;
            int s = k >> 5, h = (k & 31) >> 3, i = k & 7;
            a_lds[(((r >> 4) * NKS + s) * 64 + h * 16 + (r & 15)) * 8 + i] = 0;
        }
        __syncthreads();

        // cache per-lane row metadata (C/D map row = rb*16 + hq*4 + rg)
        unsigned pmeta[4][4];
        #pragma unroll
        for (int rb = 0; rb < 4; ++rb)
            #pragma unroll
            for (int rg = 0; rg < 4; ++rg)
                pmeta[rb][rg] = pt[rbase + rb * 16 + hq * 4 + rg];

        const int mask = um[st];
        f32x4 acc[4][2];
        #pragma unroll 1
        for (int t = 0; t < NT; ++t) {
            if (!((mask >> t) & 1)) continue;
            #pragma unroll
            for (int rb = 0; rb < 4; ++rb) {
                acc[rb][0] = (f32x4){0.f, 0.f, 0.f, 0.f};
                acc[rb][1] = (f32x4){0.f, 0.f, 0.f, 0.f};
            }
            const s16x8* bp = (const s16x8*)bfrag + (size_t)t * NKS * 8 * 64;
            #pragma unroll 1
            for (int s = 0; s < NKS; ++s) {
                s16x8 b0 = bp[(s * 8 + 2 * w + 0) * 64 + lane];
                s16x8 b1 = bp[(s * 8 + 2 * w + 1) * 64 + lane];
                bf16x8 bb0 = __builtin_bit_cast(bf16x8, b0);
                bf16x8 bb1 = __builtin_bit_cast(bf16x8, b1);
                #pragma unroll
                for (int rb = 0; rb < 4; ++rb) {
                    s16x8 araw = *(const s16x8*)&a_lds[((rb * NKS + s) * 64 + lane) * 8];
                    bf16x8 a = __builtin_bit_cast(bf16x8, araw);
                    acc[rb][0] = __builtin_amdgcn_mfma_f32_16x16x32_bf16(a, bb0, acc[rb][0], 0, 0, 0);
                    acc[rb][1] = __builtin_amdgcn_mfma_f32_16x16x32_bf16(a, bb1, acc[rb][1], 0, 0, 0);
                }
            }
            const float bias0 = bias_tab[t * OUTD + col0];
            const float bias1 = bias_tab[t * OUTD + col1];
            #pragma unroll
            for (int rb = 0; rb < 4; ++rb)
                #pragma unroll
                for (int rg = 0; rg < 4; ++rg)
                    if ((int)(pmeta[rb][rg] >> 12) == t) {
                        long e = base_e + (pmeta[rb][rg] & 0x1FF);
                        out[(size_t)e * OUTD + col0] = acc[rb][0][rg] + bias0;
                        out[(size_t)e * OUTD + col1] = acc[rb][1][rg] + bias1;
                    }
        }
        __syncthreads();   // a_lds reused next sub-tile
    }
}

// ---------------- sampled end-to-end verification (1/31 edges) ----------------
__global__ __launch_bounds__(128) void k_e2e(
    const float* __restrict__ feats, const float* __restrict__ ts,
    const int* __restrict__ types, const int* __restrict__ flag,
    const float* __restrict__ W, const float* __restrict__ b,
    const float* __restrict__ temb, const float* __restrict__ freq_rad,
    const float* __restrict__ out, int E, int* __restrict__ diag)
{
    __shared__ float srow[DIN];
    __shared__ int s_badcnt, s_big;
    const long e = (long)blockIdx.x * 31;
    if (e >= (long)E) return;
    const int n = threadIdx.x;
    if (n == 0) { s_badcnt = 0; s_big = 0; }
    const int tt = get_type(types, (int)e, *flag);
    const float tse = ts[e];
    for (int k = n; k < FEAT; k += 128) srow[k] = feats[e * FEAT + k];
    for (int j = n; j < TD; j += 128)   srow[FEAT + j] = cosf(tse * freq_rad[tt * TD + j]);
    __syncthreads();

    float acc = b[tt * OUTD + n] + temb[tt * OUTD + n];
    const float* wcol = W + (size_t)tt * DIN * OUTD + n;
    #pragma unroll 4
    for (int k = 0; k < DIN; ++k) acc += srow[k] * wcol[(size_t)k * OUTD];

    float d = fabsf(out[(size_t)e * OUTD + n] - acc);
    if (d > 0.05f) { atomicAdd(&s_badcnt, 1); if (d > 1.0f) s_big = 1; }
    __syncthreads();
    if (n == 0 && s_badcnt > 0) {
        atomicAdd(&diag[1], s_badcnt);
        atomicOr(&diag[0], s_big ? 96 : 32);
    }
}

__global__ void k_sentinel(const int* __restrict__ diag, float* __restrict__ out, int code) {
    if (threadIdx.x == 0 && blockIdx.x == 0) {
        int bits = code ? code : diag[0];
        int cnt  = code ? 0 : min(diag[1], 900000);
        if (bits != 0) out[0] = 1.0e6f * (float)(1 + bits) + (float)cnt;
    }
}

// ---------------- launch ----------------
extern "C" void kernel_launch(void* const* d_in, const int* in_sizes, int n_in,
                              void* d_out, int out_size, void* d_ws, size_t ws_size,
                              hipStream_t stream) {
    const float* feats = (const float*)d_in[0];
    const float* ts    = (const float*)d_in[1];
    const int*   types = (const int*)d_in[2];
    const float* W     = (const float*)d_in[3];
    const float* b     = (const float*)d_in[4];
    const float* temb  = (const float*)d_in[5];
    float* out = (float*)d_out;
    const int E = in_sizes[1];

    char* ws = (char*)d_ws;
    auto align256 = [](size_t x) { return (x + 255) & ~(size_t)255; };
    int* flag = (int*)(ws + 0);
    int* diag = (int*)(ws + 16);      // 2 ints
    size_t o = 256;
    float* freq_base = (float*)(ws + o); o = align256(o + TD * 4);
    float* freq_rad  = (float*)(ws + o); o = align256(o + NT * TD * 4);
    float* bias      = (float*)(ws + o); o = align256(o + NT * OUTD * 4);
    unsigned short* bfrag = (unsigned short*)(ws + o);
    o = align256(o + (size_t)NT * NKS * 8 * 64 * 8 * 2);

    if (ws_size < o) {
        k_sentinel<<<1, 64, 0, stream>>>(nullptr, out, 4);
        return;
    }

    k_init<<<1, 64, 0, stream>>>(diag);
    k_detect<<<1, 256, 0, stream>>>(types, flag);
    k_prep_tables<<<8, 256, 0, stream>>>(b, temb, freq_base, freq_rad, bias);
    k_prep_bfrag<<<(NT * NKS * 8 * 64 + 255) / 256, 256, 0, stream>>>(W, bfrag);

    int nblocks = (E + WIN - 1) / WIN;
    k_main<<<nblocks, 256, 0, stream>>>(feats, ts, types, flag, out,
                                        freq_base, bias, bfrag, E);

    k_e2e<<<(E + 30) / 31, 128, 0, stream>>>(feats, ts, types, flag, W, b, temb,
                                             freq_rad, out, E, diag);
    k_sentinel<<<1, 64, 0, stream>>>(diag, out, 0);
}

// Round 8
// 265.689 us; speedup vs baseline: 2.0555x; 1.7652x over previous
//
#include <hip/hip_runtime.h>
#include <hip/hip_bf16.h>

#define NT      8
#define TD      100
#define FEAT    172
#define DIN     272     // FEAT + TD
#define KPAD    288     // padded K, 9 * 32
#define NKS     9       // KPAD / 32
#define OUTD    128
#define BM      32      // rows per MFMA sub-tile (2 rowblocks of 16)
#define WIN     256     // edges per block (8 sub-tiles)
#define NST     (WIN / BM)
#define TWO_PI  6.283185307179586

typedef __bf16 bf16x8 __attribute__((ext_vector_type(8)));
typedef float  f32x4  __attribute__((ext_vector_type(4)));
typedef short  s16x8  __attribute__((ext_vector_type(8)));

__device__ __forceinline__ unsigned short f2bf(float f) {
    __hip_bfloat16 h = __float2bfloat16(f);        // 1-op HW convert (RNE)
    return __builtin_bit_cast(unsigned short, h);
}

// ---------------- dtype detection (int32 vs int64 edge_types) ----------------
__global__ void k_detect(const int* __restrict__ words, int* __restrict__ flag) {
    __shared__ int s_or;
    if (threadIdx.x == 0) s_or = 0;
    __syncthreads();
    int v  = words[2 * threadIdx.x + 1];
    int v2 = words[2 * (threadIdx.x + 256) + 1];
    if (v | v2) atomicOr(&s_or, 1);
    __syncthreads();
    if (threadIdx.x == 0) *flag = (s_or == 0) ? 1 : 0;   // 1 => int64
}

__device__ __forceinline__ int get_type(const int* __restrict__ p, int e, int is64) {
    return p[is64 ? (2 * e) : e] & 7;
}

// ---------------- table prep ----------------
__global__ void k_prep_tables(const float* __restrict__ b, const float* __restrict__ temb,
                              float* __restrict__ freq_base, float* __restrict__ bias) {
    int gid = blockIdx.x * blockDim.x + threadIdx.x;
    if (gid < TD)
        freq_base[gid] = (float)(pow(10.0, -(double)gid / 11.0) / TWO_PI);
    if (gid < NT * OUTD) bias[gid] = b[gid] + temb[gid];
}

// W[t][k][n] fp32 -> bf16 fragment order: bfrag[(((t*NKS+s)*8+nf)*64+lane)*8+i]
// lane: col = nf*16 + (lane&15), k = s*32 + (lane>>4)*8 + i   [HW-verified R3/R6]
__global__ void k_prep_bfrag(const float* __restrict__ W, unsigned short* __restrict__ bfrag) {
    int gid = blockIdx.x * blockDim.x + threadIdx.x;
    if (gid >= NT * NKS * 8 * 64) return;
    int lane = gid & 63;
    int rest = gid >> 6;
    int nf = rest & 7; rest >>= 3;
    int s = rest % NKS, t = rest / NKS;
    int n  = nf * 16 + (lane & 15);
    int kb = s * 32 + (lane >> 4) * 8;
    unsigned short v[8];
    #pragma unroll
    for (int i = 0; i < 8; ++i) {
        int k = kb + i;
        float x = (k < DIN) ? W[((size_t)t * DIN + k) * OUTD + n] : 0.0f;
        v[i] = f2bf(x);
    }
    unsigned short* dst = bfrag + (size_t)gid * 8;
    #pragma unroll
    for (int i = 0; i < 8; ++i) dst[i] = v[i];
}

// ---------------- main kernel: block-local type sort + per-segment MFMA ----------------
// Window = 256 consecutive edges, counting-sorted by type in LDS.
// 8 sub-tiles of 32 rows; per sub-tile, one MFMA pass per type present.
// Wave w owns output cols [w*32, w*32+32).
__global__ __launch_bounds__(256) void k_main(
    const float* __restrict__ feats, const float* __restrict__ ts,
    const int* __restrict__ types, const int* __restrict__ flag,
    float* __restrict__ out, const float* __restrict__ freq_base,
    const float* __restrict__ bias_tab, const unsigned short* __restrict__ bfrag,
    int E)
{
    __shared__ __align__(16) unsigned short a_lds[2 * NKS * 64 * 8];  // 18432 B
    __shared__ unsigned short pt[WIN];   // local_idx(8b) | type<<12 ; 0xFFFF invalid
    __shared__ float tsm[WIN];           // ts[e] * (1 + 0.1*t), by sorted slot
    __shared__ float freq_lds[TD];
    __shared__ int cnt[NT];
    __shared__ int seg[NT + 1];
    __shared__ int um[NST];              // per-sub-tile type union mask

    const int tid = threadIdx.x;
    const long base_e = (long)blockIdx.x * WIN;
    const int is64 = *flag;

    if (tid < NT)  cnt[tid] = 0;
    if (tid < NST) um[tid] = 0;
    if (tid < TD)  freq_lds[tid] = freq_base[tid];
    pt[tid] = 0xFFFF;
    tsm[tid] = 0.0f;
    __syncthreads();

    // histogram, 1 edge/thread
    int t0 = -1; float f0 = 0.f;
    {
        long e0 = base_e + tid;
        if (e0 < (long)E) {
            t0 = get_type(types, (int)e0, is64);
            f0 = ts[e0] * (1.0f + 0.1f * (float)t0);
            atomicAdd(&cnt[t0], 1);
        }
    }
    __syncthreads();
    if (tid == 0) {
        int a = 0;
        #pragma unroll
        for (int t = 0; t < NT; ++t) { seg[t] = a; a += cnt[t]; cnt[t] = 0; }
        seg[NT] = a;
    }
    __syncthreads();
    if (t0 >= 0) {
        int r = seg[t0] + atomicAdd(&cnt[t0], 1);
        pt[r] = (unsigned short)(tid | (t0 << 12));
        tsm[r] = f0;
        atomicOr(&um[r >> 5], 1 << t0);
    }
    __syncthreads();

    const int w = tid >> 6, lane = tid & 63;
    const int hq = lane >> 4, l15 = lane & 15;
    const int col0 = w * 32 + l15;        // nf = 2w
    const int col1 = w * 32 + 16 + l15;   // nf = 2w+1

    #pragma unroll 1
    for (int st = 0; st < NST; ++st) {
        const int rbase = st * BM;

        // ---- stage A, vectorized: 8 k per thread -> one ds_write_b128
        // k-group kg (8 wide): s = kg>>2, h = kg&3; lane slot = h*16 + (r&15)
        // feat full groups: kg = 0..20  (k 0..167)
        for (int idx = tid; idx < BM * 21; idx += 256) {
            int r = idx & 31, g = idx >> 5;
            unsigned p = pt[rbase + r];
            float4 fa = make_float4(0.f, 0.f, 0.f, 0.f);
            float4 fb = fa;
            if (p != 0xFFFFu) {
                const float4* src = (const float4*)feats + (base_e + (p & 0xFF)) * 43;
                fa = src[2 * g]; fb = src[2 * g + 1];
            }
            int s = g >> 2, h = g & 3;
            s16x8 v;
            v[0] = (short)f2bf(fa.x); v[1] = (short)f2bf(fa.y);
            v[2] = (short)f2bf(fa.z); v[3] = (short)f2bf(fa.w);
            v[4] = (short)f2bf(fb.x); v[5] = (short)f2bf(fb.y);
            v[6] = (short)f2bf(fb.z); v[7] = (short)f2bf(fb.w);
            *(s16x8*)&a_lds[(((r >> 4) * NKS + s) * 64 + h * 16 + (r & 15)) * 8] = v;
        }
        // bridge group kg=21 (k 168..175): 4 feat + 4 cos  (s=5, h=1)
        for (int idx = tid; idx < BM; idx += 256) {
            int r = idx;
            unsigned p = pt[rbase + r];
            float tm = tsm[rbase + r];
            float4 fa = make_float4(0.f, 0.f, 0.f, 0.f);
            if (p != 0xFFFFu)
                fa = ((const float4*)feats)[(base_e + (p & 0xFF)) * 43 + 42];
            s16x8 v;
            v[0] = (short)f2bf(fa.x); v[1] = (short)f2bf(fa.y);
            v[2] = (short)f2bf(fa.z); v[3] = (short)f2bf(fa.w);
            #pragma unroll
            for (int i = 0; i < 4; ++i) {
                float rev = tm * freq_lds[i];
                float fr  = rev - floorf(rev);
                v[4 + i] = (short)f2bf(__builtin_amdgcn_cosf(fr));
            }
            *(s16x8*)&a_lds[(((r >> 4) * NKS + 5) * 64 + 1 * 16 + (r & 15)) * 8] = v;
        }
        // cos full groups: kg = 22..33  (k 176..271, j = 4..99)
        for (int idx = tid; idx < BM * 12; idx += 256) {
            int r = idx & 31, gg = idx >> 5;
            float tm = tsm[rbase + r];
            int kg = 22 + gg;
            int s = kg >> 2, h = kg & 3;
            int j0 = kg * 8 - FEAT;
            s16x8 v;
            #pragma unroll
            for (int i = 0; i < 8; ++i) {
                float rev = tm * freq_lds[j0 + i];
                float fr  = rev - floorf(rev);
                v[i] = (short)f2bf(__builtin_amdgcn_cosf(fr));
            }
            *(s16x8*)&a_lds[(((r >> 4) * NKS + s) * 64 + h * 16 + (r & 15)) * 8] = v;
        }
        // zero pad: kg = 34..35 (k 272..287)
        for (int idx = tid; idx < BM * 2; idx += 256) {
            int r = idx & 31, gg = idx >> 5;
            int kg = 34 + gg;
            int s = kg >> 2, h = kg & 3;
            s16x8 v = (s16x8){0, 0, 0, 0, 0, 0, 0, 0};
            *(s16x8*)&a_lds[(((r >> 4) * NKS + s) * 64 + h * 16 + (r & 15)) * 8] = v;
        }
        __syncthreads();

        // per-lane row metadata (C/D map: row = rb*16 + hq*4 + rg, m89-verified)
        unsigned pmeta[2][4];
        #pragma unroll
        for (int rb = 0; rb < 2; ++rb)
            #pragma unroll
            for (int rg = 0; rg < 4; ++rg)
                pmeta[rb][rg] = pt[rbase + rb * 16 + hq * 4 + rg];

        const int mask = um[st];
        f32x4 acc[2][2];
        #pragma unroll 1
        for (int t = 0; t < NT; ++t) {
            if (!((mask >> t) & 1)) continue;
            #pragma unroll
            for (int rb = 0; rb < 2; ++rb) {
                acc[rb][0] = (f32x4){0.f, 0.f, 0.f, 0.f};
                acc[rb][1] = (f32x4){0.f, 0.f, 0.f, 0.f};
            }
            const s16x8* bp = (const s16x8*)bfrag + (size_t)t * NKS * 8 * 64;
            #pragma unroll 1
            for (int s = 0; s < NKS; ++s) {
                s16x8 b0 = bp[(s * 8 + 2 * w + 0) * 64 + lane];
                s16x8 b1 = bp[(s * 8 + 2 * w + 1) * 64 + lane];
                bf16x8 bb0 = __builtin_bit_cast(bf16x8, b0);
                bf16x8 bb1 = __builtin_bit_cast(bf16x8, b1);
                #pragma unroll
                for (int rb = 0; rb < 2; ++rb) {
                    s16x8 araw = *(const s16x8*)&a_lds[((rb * NKS + s) * 64 + lane) * 8];
                    bf16x8 a = __builtin_bit_cast(bf16x8, araw);
                    acc[rb][0] = __builtin_amdgcn_mfma_f32_16x16x32_bf16(a, bb0, acc[rb][0], 0, 0, 0);
                    acc[rb][1] = __builtin_amdgcn_mfma_f32_16x16x32_bf16(a, bb1, acc[rb][1], 0, 0, 0);
                }
            }
            const float bias0 = bias_tab[t * OUTD + col0];
            const float bias1 = bias_tab[t * OUTD + col1];
            #pragma unroll
            for (int rb = 0; rb < 2; ++rb)
                #pragma unroll
                for (int rg = 0; rg < 4; ++rg)
                    if ((int)(pmeta[rb][rg] >> 12) == t) {
                        long e = base_e + (pmeta[rb][rg] & 0xFF);
                        out[(size_t)e * OUTD + col0] = acc[rb][0][rg] + bias0;
                        out[(size_t)e * OUTD + col1] = acc[rb][1][rg] + bias1;
                    }
        }
        __syncthreads();   // a_lds reused next sub-tile
    }
}

// ---------------- launch ----------------
extern "C" void kernel_launch(void* const* d_in, const int* in_sizes, int n_in,
                              void* d_out, int out_size, void* d_ws, size_t ws_size,
                              hipStream_t stream) {
    const float* feats = (const float*)d_in[0];
    const float* ts    = (const float*)d_in[1];
    const int*   types = (const int*)d_in[2];
    const float* W     = (const float*)d_in[3];
    const float* b     = (const float*)d_in[4];
    const float* temb  = (const float*)d_in[5];
    float* out = (float*)d_out;
    const int E = in_sizes[1];

    char* ws = (char*)d_ws;
    auto align256 = [](size_t x) { return (x + 255) & ~(size_t)255; };
    int* flag = (int*)(ws + 0);
    size_t o = 256;
    float* freq_base = (float*)(ws + o); o = align256(o + TD * 4);
    float* bias      = (float*)(ws + o); o = align256(o + NT * OUTD * 4);
    unsigned short* bfrag = (unsigned short*)(ws + o);
    o = align256(o + (size_t)NT * NKS * 8 * 64 * 8 * 2);
    if (ws_size < o) return;   // never expected; prior rounds confirm ws is ample

    k_detect<<<1, 256, 0, stream>>>(types, flag);
    k_prep_tables<<<8, 256, 0, stream>>>(b, temb, freq_base, bias);
    k_prep_bfrag<<<(NT * NKS * 8 * 64 + 255) / 256, 256, 0, stream>>>(W, bfrag);

    int nblocks = (E + WIN - 1) / WIN;
    k_main<<<nblocks, 256, 0, stream>>>(feats, ts, types, flag, out,
                                        freq_base, bias, bfrag, E);
}

// Round 9
// 229.952 us; speedup vs baseline: 2.3750x; 1.1554x over previous
//
#include <hip/hip_runtime.h>
#include <hip/hip_bf16.h>

#define NT      8
#define TD      100
#define FEAT    172
#define DIN     272     // FEAT + TD
#define KPAD    288     // padded K, 9 * 32
#define NKS     9       // KPAD / 32
#define OUTD    128
#define BM      32      // rows per MFMA sub-tile (2 rowblocks of 16)
#define WIN     256     // edges per block (8 sub-tiles)
#define NST     (WIN / BM)
#define TWO_PI  6.283185307179586

typedef __bf16 bf16x8 __attribute__((ext_vector_type(8)));
typedef float  f32x4  __attribute__((ext_vector_type(4)));
typedef short  s16x8  __attribute__((ext_vector_type(8)));

__device__ __forceinline__ unsigned short f2bf(float f) {
    __hip_bfloat16 h = __float2bfloat16(f);        // 1-op HW convert (RNE)
    return __builtin_bit_cast(unsigned short, h);
}

// ---------------- dtype detection (int32 vs int64 edge_types) ----------------
__global__ void k_detect(const int* __restrict__ words, int* __restrict__ flag) {
    __shared__ int s_or;
    if (threadIdx.x == 0) s_or = 0;
    __syncthreads();
    int v  = words[2 * threadIdx.x + 1];
    int v2 = words[2 * (threadIdx.x + 256) + 1];
    if (v | v2) atomicOr(&s_or, 1);
    __syncthreads();
    if (threadIdx.x == 0) *flag = (s_or == 0) ? 1 : 0;   // 1 => int64
}

__device__ __forceinline__ int get_type(const int* __restrict__ p, int e, int is64) {
    return p[is64 ? (2 * e) : e] & 7;
}

// ---------------- table prep ----------------
__global__ void k_prep_tables(const float* __restrict__ b, const float* __restrict__ temb,
                              float* __restrict__ freq_base, float* __restrict__ bias) {
    int gid = blockIdx.x * blockDim.x + threadIdx.x;
    if (gid < TD)
        freq_base[gid] = (float)(pow(10.0, -(double)gid / 11.0) / TWO_PI);
    if (gid < NT * OUTD) bias[gid] = b[gid] + temb[gid];
}

// W[t][k][n] fp32 -> bf16 fragment order: bfrag[(((t*NKS+s)*8+nf)*64+lane)*8+i]
// lane: col = nf*16 + (lane&15), k = s*32 + (lane>>4)*8 + i   [HW-verified R3/R6]
__global__ void k_prep_bfrag(const float* __restrict__ W, unsigned short* __restrict__ bfrag) {
    int gid = blockIdx.x * blockDim.x + threadIdx.x;
    if (gid >= NT * NKS * 8 * 64) return;
    int lane = gid & 63;
    int rest = gid >> 6;
    int nf = rest & 7; rest >>= 3;
    int s = rest % NKS, t = rest / NKS;
    int n  = nf * 16 + (lane & 15);
    int kb = s * 32 + (lane >> 4) * 8;
    unsigned short v[8];
    #pragma unroll
    for (int i = 0; i < 8; ++i) {
        int k = kb + i;
        float x = (k < DIN) ? W[((size_t)t * DIN + k) * OUTD + n] : 0.0f;
        v[i] = f2bf(x);
    }
    unsigned short* dst = bfrag + (size_t)gid * 8;
    #pragma unroll
    for (int i = 0; i < 8; ++i) dst[i] = v[i];
}

// ---------------- main kernel: 512 threads, 2 wave-groups ping-pong ----------------
// Window = 256 consecutive edges, counting-sorted by type in LDS.
// Group g (waves 4g..4g+3) owns a_lds[g] and subtiles {g, g+2, g+4, g+6}:
// step i: group (i&1) stages subtile i  ||  group ((i-1)&1) MFMAs subtile i-1.
__global__ __launch_bounds__(512, 6) void k_main(
    const float* __restrict__ feats, const float* __restrict__ ts,
    const int* __restrict__ types, const int* __restrict__ flag,
    float* __restrict__ out, const float* __restrict__ freq_base,
    const float* __restrict__ bias_tab, const unsigned short* __restrict__ bfrag,
    int E)
{
    __shared__ __align__(16) unsigned short a_lds[2][2 * NKS * 64 * 8]; // 2x18432 B
    __shared__ unsigned short pt[WIN];   // local_idx(8b) | type<<12 ; 0xFFFF invalid
    __shared__ float tsm[WIN];           // ts[e] * (1 + 0.1*t), by sorted slot
    __shared__ float freq_lds[TD];
    __shared__ int cnt[NT];
    __shared__ int seg[NT + 1];
    __shared__ int um[NST];              // per-sub-tile type union mask

    const int tid = threadIdx.x;
    const long base_e = (long)blockIdx.x * WIN;
    const int is64 = *flag;

    if (tid < NT)  cnt[tid] = 0;
    if (tid < NST) um[tid] = 0;
    if (tid < TD)  freq_lds[tid] = freq_base[tid];
    if (tid < WIN) { pt[tid] = 0xFFFF; tsm[tid] = 0.0f; }
    __syncthreads();

    // counting sort (threads 0..255 handle one edge each)
    int t0 = -1; float f0 = 0.f;
    if (tid < WIN) {
        long e0 = base_e + tid;
        if (e0 < (long)E) {
            t0 = get_type(types, (int)e0, is64);
            f0 = ts[e0] * (1.0f + 0.1f * (float)t0);
            atomicAdd(&cnt[t0], 1);
        }
    }
    __syncthreads();
    if (tid == 0) {
        int a = 0;
        #pragma unroll
        for (int t = 0; t < NT; ++t) { seg[t] = a; a += cnt[t]; cnt[t] = 0; }
        seg[NT] = a;
    }
    __syncthreads();
    if (t0 >= 0) {
        int r = seg[t0] + atomicAdd(&cnt[t0], 1);
        pt[r] = (unsigned short)(tid | (t0 << 12));
        tsm[r] = f0;
        atomicOr(&um[r >> 5], 1 << t0);
    }
    __syncthreads();

    const int g    = tid >> 8;          // wave-group 0/1
    const int tg   = tid & 255;         // thread within group
    const int w    = (tid >> 6) & 3;    // wave within group
    const int lane = tid & 63;
    const int hq = lane >> 4, l15 = lane & 15;
    const int col0 = w * 32 + l15;      // nf = 2w
    const int col1 = col0 + 16;         // nf = 2w+1

    #pragma unroll 1
    for (int i = 0; i <= NST; ++i) {
        // ================= STAGE subtile i (group i&1) =================
        if (i < NST && (i & 1) == g) {
            unsigned short* A = a_lds[g];
            const int rbase = i * BM;

            // feat groups kg 0..21 (kg=21 bridges 4 feat + 4 cos), kg-minor
            // for line-dense global reads (consecutive lanes = same row).
            for (int idx = tg; idx < BM * 22; idx += 256) {
                int slot = idx / 22, kg = idx - slot * 22;
                unsigned p = pt[rbase + slot];
                float tm = tsm[rbase + slot];
                float4 fa = make_float4(0.f, 0.f, 0.f, 0.f);
                float4 fb = fa;
                if (p != 0xFFFFu) {
                    const float4* src = (const float4*)feats + (base_e + (p & 0xFF)) * 43;
                    fa = src[2 * kg];
                    if (kg < 21) fb = src[2 * kg + 1];
                }
                s16x8 v;
                v[0] = (short)f2bf(fa.x); v[1] = (short)f2bf(fa.y);
                v[2] = (short)f2bf(fa.z); v[3] = (short)f2bf(fa.w);
                if (kg < 21) {
                    v[4] = (short)f2bf(fb.x); v[5] = (short)f2bf(fb.y);
                    v[6] = (short)f2bf(fb.z); v[7] = (short)f2bf(fb.w);
                } else {
                    #pragma unroll
                    for (int q = 0; q < 4; ++q) {
                        float rev = tm * freq_lds[q];
                        float fr  = rev - floorf(rev);
                        v[4 + q] = (short)f2bf(__builtin_amdgcn_cosf(fr));
                    }
                }
                int s = kg >> 2, h = kg & 3;
                *(s16x8*)&A[(((slot >> 4) * NKS + s) * 64 + h * 16 + (slot & 15)) * 8] = v;
            }
            // cos full groups kg 22..33 (slot-minor: conflict-free writes)
            for (int idx = tg; idx < BM * 12; idx += 256) {
                int slot = idx & 31, gg = idx >> 5;
                float tm = tsm[rbase + slot];
                int kg = 22 + gg;
                int s = kg >> 2, h = kg & 3;
                int j0 = kg * 8 - FEAT;
                s16x8 v;
                #pragma unroll
                for (int q = 0; q < 8; ++q) {
                    float rev = tm * freq_lds[j0 + q];
                    float fr  = rev - floorf(rev);
                    v[q] = (short)f2bf(__builtin_amdgcn_cosf(fr));
                }
                *(s16x8*)&A[(((slot >> 4) * NKS + s) * 64 + h * 16 + (slot & 15)) * 8] = v;
            }
            // zero pad kg 34,35 (k 272..287)
            for (int idx = tg; idx < BM * 2; idx += 256) {
                int slot = idx & 31, gg = idx >> 5;
                int kg = 34 + gg;
                int s = kg >> 2, h = kg & 3;
                s16x8 v = (s16x8){0, 0, 0, 0, 0, 0, 0, 0};
                *(s16x8*)&A[(((slot >> 4) * NKS + s) * 64 + h * 16 + (slot & 15)) * 8] = v;
            }
        }
        // ================= MFMA subtile i-1 (group (i-1)&1) =================
        if (i >= 1 && ((i - 1) & 1) == g) {
            const unsigned short* A = a_lds[g];
            const int rbase = (i - 1) * BM;
            const int mask = um[i - 1];
            f32x4 acc[2][2];
            #pragma unroll 1
            for (int t = 0; t < NT; ++t) {
                if (!((mask >> t) & 1)) continue;
                #pragma unroll
                for (int rb = 0; rb < 2; ++rb) {
                    acc[rb][0] = (f32x4){0.f, 0.f, 0.f, 0.f};
                    acc[rb][1] = (f32x4){0.f, 0.f, 0.f, 0.f};
                }
                const s16x8* bp = (const s16x8*)bfrag + (size_t)t * NKS * 8 * 64;
                // software-pipelined B: prefetch next s-step before using current
                s16x8 nb0 = bp[(2 * w + 0) * 64 + lane];
                s16x8 nb1 = bp[(2 * w + 1) * 64 + lane];
                #pragma unroll 1
                for (int s = 0; s < NKS; ++s) {
                    s16x8 b0 = nb0, b1 = nb1;
                    if (s + 1 < NKS) {
                        nb0 = bp[((s + 1) * 8 + 2 * w + 0) * 64 + lane];
                        nb1 = bp[((s + 1) * 8 + 2 * w + 1) * 64 + lane];
                    }
                    bf16x8 bb0 = __builtin_bit_cast(bf16x8, b0);
                    bf16x8 bb1 = __builtin_bit_cast(bf16x8, b1);
                    #pragma unroll
                    for (int rb = 0; rb < 2; ++rb) {
                        s16x8 araw = *(const s16x8*)&A[((rb * NKS + s) * 64 + lane) * 8];
                        bf16x8 a = __builtin_bit_cast(bf16x8, araw);
                        acc[rb][0] = __builtin_amdgcn_mfma_f32_16x16x32_bf16(a, bb0, acc[rb][0], 0, 0, 0);
                        acc[rb][1] = __builtin_amdgcn_mfma_f32_16x16x32_bf16(a, bb1, acc[rb][1], 0, 0, 0);
                    }
                }
                const float bias0 = bias_tab[t * OUTD + col0];
                const float bias1 = bias_tab[t * OUTD + col1];
                #pragma unroll
                for (int rb = 0; rb < 2; ++rb)
                    #pragma unroll
                    for (int rg = 0; rg < 4; ++rg) {
                        unsigned p = pt[rbase + rb * 16 + hq * 4 + rg];
                        if ((int)(p >> 12) == t) {
                            long e = base_e + (p & 0xFF);
                            out[(size_t)e * OUTD + col0] = acc[rb][0][rg] + bias0;
                            out[(size_t)e * OUTD + col1] = acc[rb][1][rg] + bias1;
                        }
                    }
            }
        }
        __syncthreads();
    }
}

// ---------------- launch ----------------
extern "C" void kernel_launch(void* const* d_in, const int* in_sizes, int n_in,
                              void* d_out, int out_size, void* d_ws, size_t ws_size,
                              hipStream_t stream) {
    const float* feats = (const float*)d_in[0];
    const float* ts    = (const float*)d_in[1];
    const int*   types = (const int*)d_in[2];
    const float* W     = (const float*)d_in[3];
    const float* b     = (const float*)d_in[4];
    const float* temb  = (const float*)d_in[5];
    float* out = (float*)d_out;
    const int E = in_sizes[1];

    char* ws = (char*)d_ws;
    auto align256 = [](size_t x) { return (x + 255) & ~(size_t)255; };
    int* flag = (int*)(ws + 0);
    size_t o = 256;
    float* freq_base = (float*)(ws + o); o = align256(o + TD * 4);
    float* bias      = (float*)(ws + o); o = align256(o + NT * OUTD * 4);
    unsigned short* bfrag = (unsigned short*)(ws + o);
    o = align256(o + (size_t)NT * NKS * 8 * 64 * 8 * 2);
    if (ws_size < o) return;   // never expected; prior rounds confirm ws is ample

    k_detect<<<1, 256, 0, stream>>>(types, flag);
    k_prep_tables<<<8, 256, 0, stream>>>(b, temb, freq_base, bias);
    k_prep_bfrag<<<(NT * NKS * 8 * 64 + 255) / 256, 256, 0, stream>>>(W, bfrag);

    int nblocks = (E + WIN - 1) / WIN;
    k_main<<<nblocks, 512, 0, stream>>>(feats, ts, types, flag, out,
                                        freq_base, bias, bfrag, E);
}